// Round 2
// baseline (582.180 us; speedup 1.0000x reference)
//
#include <hip/hip_runtime.h>
#include <math.h>

// Crop-and-resize (bilinear) — x:(B,H,W,4) f32, boxes:(B,4) f32 [y1,x1,y2,x2],
// out:(B,crop,crop,4) f32. Grid = (1, crop, B): one block per output row.
// b, i are block-uniform -> box load + vertical coords go to SALU; each lane
// handles one output column j with a single float4 store (coalesced) and four
// float4 gather taps (row-uniform base + monotone lane offsets -> L1/L2
// segment hits).

__global__ __launch_bounds__(256) void crop_resize_kernel(
    const float* __restrict__ x,
    const float* __restrict__ boxes,
    float4* __restrict__ out,
    int B, int H, int W, int crop)
{
    int j = threadIdx.x;           // output x (0..crop-1), coalesced
    int i = blockIdx.y;            // output y — block-uniform
    int b = blockIdx.z;            // batch   — block-uniform
    if (j >= crop) return;

    // box coords (block-uniform -> scalar loads)
    float y1 = boxes[b * 4 + 0];
    float x1 = boxes[b * 4 + 1];
    float y2 = boxes[b * 4 + 2];
    float x2 = boxes[b * 4 + 3];

    float cm1 = (float)(crop - 1);
    float gy = (float)i / cm1;     // match reference: arange/(crop-1), real divide
    float gx = (float)j / cm1;

    float Hm1 = (float)(H - 1);
    float Wm1 = (float)(W - 1);
    float in_y = (y1 + gy * (y2 - y1)) * Hm1;   // uniform
    float in_x = (x1 + gx * (x2 - x1)) * Wm1;   // per-lane

    bool valid = (in_y >= 0.0f) && (in_y <= Hm1) && (in_x >= 0.0f) && (in_x <= Wm1);

    float top_f  = floorf(in_y);
    float left_f = floorf(in_x);
    float yl = in_y - top_f;       // uniform
    float xl = in_x - left_f;      // per-lane

    int t  = min(max((int)top_f, 0), H - 1);    // uniform
    int bb = min(t + 1, H - 1);                 // uniform
    int l  = min(max((int)left_f, 0), W - 1);
    int r  = min(l + 1, W - 1);

    const float4* __restrict__ xb = (const float4*)x + (size_t)b * H * W;
    size_t rowT = (size_t)t * W;
    size_t rowB = (size_t)bb * W;

    float4 tl = xb[rowT + l];
    float4 tr = xb[rowT + r];
    float4 bl = xb[rowB + l];
    float4 br = xb[rowB + r];

    float4 o;
    {
        float top0 = tl.x + (tr.x - tl.x) * xl;
        float bot0 = bl.x + (br.x - bl.x) * xl;
        o.x = top0 + (bot0 - top0) * yl;
        float top1 = tl.y + (tr.y - tl.y) * xl;
        float bot1 = bl.y + (br.y - bl.y) * xl;
        o.y = top1 + (bot1 - top1) * yl;
        float top2 = tl.z + (tr.z - tl.z) * xl;
        float bot2 = bl.z + (br.z - bl.z) * xl;
        o.z = top2 + (bot2 - top2) * yl;
        float top3 = tl.w + (tr.w - tl.w) * xl;
        float bot3 = bl.w + (br.w - bl.w) * xl;
        o.w = top3 + (bot3 - top3) * yl;
    }

    if (!valid) o = make_float4(0.0f, 0.0f, 0.0f, 0.0f);

    out[((size_t)b * crop + i) * crop + j] = o;
}

extern "C" void kernel_launch(void* const* d_in, const int* in_sizes, int n_in,
                              void* d_out, int out_size, void* d_ws, size_t ws_size,
                              hipStream_t stream)
{
    const float* x     = (const float*)d_in[0];
    const float* boxes = (const float*)d_in[1];
    // d_in[2] is out_im_res (device int) — derive sizes on host instead.

    const int C = 4;
    int B = in_sizes[1] / 4;                       // boxes is (B,4)
    long long hw = (long long)in_sizes[0] / ((long long)B * C);
    int H = (int)(sqrt((double)hw) + 0.5);         // H == W == 1024
    int W = H;
    long long cc = (long long)out_size / ((long long)B * C);
    int crop = (int)(sqrt((double)cc) + 0.5);      // 224

    dim3 block(256, 1, 1);
    dim3 grid(1, (unsigned)crop, (unsigned)B);

    crop_resize_kernel<<<grid, block, 0, stream>>>(
        x, boxes, (float4*)d_out, B, H, W, crop);
}